// Round 14
// baseline (106.378 us; speedup 1.0000x reference)
//
#include <hip/hip_runtime.h>

#define N_ATOMS 100000
#define N_EDGES 625000
#define N_MOL   1000
#define EMB_ATOM 256
#define EMB_EDGE 128

typedef float f32x4 __attribute__((ext_vector_type(4)));

__device__ __forceinline__ float dot4(f32x4 a, f32x4 b) {
    return a.x * b.x + a.y * b.y + a.z * b.z + a.w * b.w;
}

// ---- workspace layout (floats) ----
// rep_y : 8 replicas x 1024   at ws[0 .. 8192)
// rep_f : 8 replicas x 300000 at ws[8192 .. 2408192)
#define REP      8
#define YREP_STR 1024
#define FREP_OFF 8192
#define FREP_STR 300000
#define WS_FLOATS (FREP_OFF + REP * FREP_STR)    // 2408192 (= 602048 f32x4)

__global__ __launch_bounds__(256) void zero_kernel(f32x4* __restrict__ p, int n4)
{
    const int i = blockIdx.x * blockDim.x + threadIdx.x;
    if (i < n4) p[i] = (f32x4)(0.f, 0.f, 0.f, 0.f);
}

// Merge replicas into d_out. f32x4 elements 0..249 are y (1000 floats),
// 250..75249 are force (300000 floats).
__global__ __launch_bounds__(256) void merge_kernel(
    const float* __restrict__ ws, float* __restrict__ out)
{
    const int i = blockIdx.x * blockDim.x + threadIdx.x;
    if (i >= 250 + 75000) return;
    const f32x4* w4 = reinterpret_cast<const f32x4*>(ws);
    f32x4*       o4 = reinterpret_cast<f32x4*>(out);
    if (i < 250) {
        f32x4 s = (f32x4)(0.f, 0.f, 0.f, 0.f);
        #pragma unroll
        for (int k = 0; k < REP; ++k) s += w4[i + k * (YREP_STR/4)];
        o4[i] = s;
    } else {
        const int j = i - 250;
        const f32x4* f4 = w4 + FREP_OFF/4;
        f32x4 s = (f32x4)(0.f, 0.f, 0.f, 0.f);
        #pragma unroll
        for (int k = 0; k < REP; ++k) s += f4[j + k * (FREP_STR/4)];
        o4[i] = s;
    }
}

// Fused persistent kernel — R12 structure exactly, single change: the
// streaming loads are PLAIN (no nontemporal hint). A/B vs R12's 96.8 us
// isolates the NT hint on this base.
#define FTILES  ((N_EDGES + 15) / 16)            // 39063
#define FPBLOCKS 1960                            // 7840 wave-slots
#define ETILES  (N_ATOMS / 8)                    // 12500 exact
#define EPBLOCKS 600                             // 2400 wave-slots

__global__ __launch_bounds__(256) void fused_kernel(
    const float* __restrict__ h_energy,
    const float* __restrict__ h_forces,
    const float* __restrict__ V_st,
    const int*   __restrict__ idx_t,
    const int*   __restrict__ batch_idx,
    const float* __restrict__ W_energy,
    const float* __restrict__ W_forces,
    const float* __restrict__ b_forces,
    float*       __restrict__ ws)
{
    const int lane = threadIdx.x & 63;

    if (blockIdx.x < FPBLOCKS) {
        // ---------------- forces ----------------
        const int wslot = blockIdx.x * 4 + (threadIdx.x >> 6);
        const int slot  = lane >> 3;     // 0..7 : edge slot
        const int sub   = lane & 7;      // 0..7 : position within edge row

        const f32x4* wf   = reinterpret_cast<const f32x4*>(W_forces);
        const f32x4* base = reinterpret_cast<const f32x4*>(h_forces); // row = 32 f32x4
        float* frep = ws + FREP_OFF + (wslot & (REP-1)) * FREP_STR;

        f32x4 b0 = wf[sub + 0];
        f32x4 b1 = wf[sub + 8];
        f32x4 b2 = wf[sub + 16];
        f32x4 b3 = wf[sub + 24];
        const float bias = b_forces[0];

        for (int tile = wslot; tile < FTILES; tile += FPBLOCKS * 4) {
            #pragma unroll
            for (int g = 0; g < 2; ++g) {
                const int e = tile * 16 + g * 8 + slot;
                float s = 0.f;
                if (e < N_EDGES) {
                    const f32x4* row = base + (size_t)e * 32;
                    f32x4 a0 = row[sub + 0];
                    f32x4 a1 = row[sub + 8];
                    f32x4 a2 = row[sub + 16];
                    f32x4 a3 = row[sub + 24];
                    s = dot4(a0, b0) + dot4(a1, b1) + dot4(a2, b2) + dot4(a3, b3);
                }
                s += __shfl_xor(s, 1, 64);
                s += __shfl_xor(s, 2, 64);
                s += __shfl_xor(s, 4, 64);
                if (e < N_EDGES && sub < 3) {
                    const int   t = idx_t[e];
                    const float v = V_st[(size_t)e * 3 + sub];
                    atomicAdd(&frep[(size_t)t * 3 + sub], (s + bias) * v);
                }
            }
        }
    } else if (blockIdx.x < FPBLOCKS + EPBLOCKS) {
        // ---------------- energy ----------------
        const int wslot = (blockIdx.x - FPBLOCKS) * 4 + (threadIdx.x >> 6);
        const int slot  = lane >> 4;     // 0..3 : atom slot
        const int sub   = lane & 15;     // 0..15: position within atom row

        const f32x4* we   = reinterpret_cast<const f32x4*>(W_energy);
        const f32x4* base = reinterpret_cast<const f32x4*>(h_energy); // row = 64 f32x4
        float* yrep = ws + (wslot & (REP-1)) * YREP_STR;

        f32x4 b0 = we[sub + 0];
        f32x4 b1 = we[sub + 16];
        f32x4 b2 = we[sub + 32];
        f32x4 b3 = we[sub + 48];

        for (int tile = wslot; tile < ETILES; tile += EPBLOCKS * 4) {
            #pragma unroll
            for (int g = 0; g < 2; ++g) {
                const int a = tile * 8 + g * 4 + slot;   // < 100000 exact
                const f32x4* row = base + (size_t)a * 64;
                f32x4 a0 = row[sub + 0];
                f32x4 a1 = row[sub + 16];
                f32x4 a2 = row[sub + 32];
                f32x4 a3 = row[sub + 48];
                float s = dot4(a0, b0) + dot4(a1, b1) + dot4(a2, b2) + dot4(a3, b3);

                s += __shfl_xor(s, 1, 64);
                s += __shfl_xor(s, 2, 64);
                s += __shfl_xor(s, 4, 64);
                s += __shfl_xor(s, 8, 64);

                if (sub == 0) atomicAdd(&yrep[batch_idx[a]], s);
            }
        }
    }
}

extern "C" void kernel_launch(void* const* d_in, const int* in_sizes, int n_in,
                              void* d_out, int out_size, void* d_ws, size_t ws_size,
                              hipStream_t stream) {
    const float* h_energy  = (const float*)d_in[0];
    const float* h_forces  = (const float*)d_in[1];
    const float* V_st      = (const float*)d_in[2];
    const int*   idx_t     = (const int*)d_in[3];
    const int*   batch_idx = (const int*)d_in[4];
    const float* W_energy  = (const float*)d_in[5];
    const float* W_forces  = (const float*)d_in[6];
    const float* b_forces  = (const float*)d_in[7];

    float* ws  = (float*)d_ws;
    float* out = (float*)d_out;

    // Zero replica accumulators (2408192 floats = 602048 f32x4 = 9.6 MB).
    const int zn4 = WS_FLOATS / 4;
    zero_kernel<<<(zn4 + 255) / 256, 256, 0, stream>>>((f32x4*)d_ws, zn4);

    // Fused persistent kernel: 1960 forces + 600 energy blocks.
    fused_kernel<<<FPBLOCKS + EPBLOCKS, 256, 0, stream>>>(
        h_energy, h_forces, V_st, idx_t, batch_idx,
        W_energy, W_forces, b_forces, ws);

    // Merge replicas -> d_out (75250 f32x4 elements).
    merge_kernel<<<(75250 + 255) / 256, 256, 0, stream>>>(ws, out);
}

// Round 15
// 98.527 us; speedup vs baseline: 1.0797x; 1.0797x over previous
//
#include <hip/hip_runtime.h>

#define N_ATOMS 100000
#define N_EDGES 625000
#define N_MOL   1000
#define EMB_ATOM 256
#define EMB_EDGE 128

typedef float f32x4 __attribute__((ext_vector_type(4)));

__device__ __forceinline__ float dot4(f32x4 a, f32x4 b) {
    return a.x * b.x + a.y * b.y + a.z * b.z + a.w * b.w;
}

// ---- workspace layout (floats) ----
// rep_y : 8 replicas x 1024   at ws[0 .. 8192)
// rep_f : 8 replicas x 300000 at ws[8192 .. 2408192)
#define REP      8
#define YREP_STR 1024
#define FREP_OFF 8192
#define FREP_STR 300000
#define WS_FLOATS (FREP_OFF + REP * FREP_STR)    // 2408192 (= 602048 f32x4)

__global__ __launch_bounds__(256) void zero_kernel(f32x4* __restrict__ p, int n4)
{
    const int i = blockIdx.x * blockDim.x + threadIdx.x;
    if (i < n4) p[i] = (f32x4)(0.f, 0.f, 0.f, 0.f);
}

// Merge replicas into d_out. f32x4 elements 0..249 are y (1000 floats),
// 250..75249 are force (300000 floats).
__global__ __launch_bounds__(256) void merge_kernel(
    const float* __restrict__ ws, float* __restrict__ out)
{
    const int i = blockIdx.x * blockDim.x + threadIdx.x;
    if (i >= 250 + 75000) return;
    const f32x4* w4 = reinterpret_cast<const f32x4*>(ws);
    f32x4*       o4 = reinterpret_cast<f32x4*>(out);
    if (i < 250) {
        f32x4 s = (f32x4)(0.f, 0.f, 0.f, 0.f);
        #pragma unroll
        for (int k = 0; k < REP; ++k) s += w4[i + k * (YREP_STR/4)];
        o4[i] = s;
    } else {
        const int j = i - 250;
        const f32x4* f4 = w4 + FREP_OFF/4;
        f32x4 s = (f32x4)(0.f, 0.f, 0.f, 0.f);
        #pragma unroll
        for (int k = 0; k < REP; ++k) s += f4[j + k * (FREP_STR/4)];
        o4[i] = s;
    }
}

// Fused persistent kernel — R12 body (NT loads), grid sized for guaranteed
// residency: 1536 blocks = 6 blocks/CU x 256 CU (launch_bounds(256,6) caps
// VGPR at ~84 > the ~60 this body needs). Previous 2560-block grid was 1.25x
// oversubscribed -> serialized second round of blocks (R14 post-mortem).
// Split by traffic ratio 330MB:102MB -> 1172 : 364 (70.5 KB per wave-slot
// on both sides).
#define FTILES   ((N_EDGES + 15) / 16)           // 39063
#define FPBLOCKS 1172                            // 4688 wave-slots
#define ETILES   (N_ATOMS / 8)                   // 12500 exact
#define EPBLOCKS 364                             // 1456 wave-slots

__global__ __launch_bounds__(256, 6) void fused_kernel(
    const float* __restrict__ h_energy,
    const float* __restrict__ h_forces,
    const float* __restrict__ V_st,
    const int*   __restrict__ idx_t,
    const int*   __restrict__ batch_idx,
    const float* __restrict__ W_energy,
    const float* __restrict__ W_forces,
    const float* __restrict__ b_forces,
    float*       __restrict__ ws)
{
    const int lane = threadIdx.x & 63;

    if (blockIdx.x < FPBLOCKS) {
        // ---------------- forces ----------------
        const int wslot = blockIdx.x * 4 + (threadIdx.x >> 6);
        const int slot  = lane >> 3;     // 0..7 : edge slot
        const int sub   = lane & 7;      // 0..7 : position within edge row

        const f32x4* wf   = reinterpret_cast<const f32x4*>(W_forces);
        const f32x4* base = reinterpret_cast<const f32x4*>(h_forces); // row = 32 f32x4
        float* frep = ws + FREP_OFF + (wslot & (REP-1)) * FREP_STR;

        f32x4 b0 = wf[sub + 0];
        f32x4 b1 = wf[sub + 8];
        f32x4 b2 = wf[sub + 16];
        f32x4 b3 = wf[sub + 24];
        const float bias = b_forces[0];

        for (int tile = wslot; tile < FTILES; tile += FPBLOCKS * 4) {
            #pragma unroll
            for (int g = 0; g < 2; ++g) {
                const int e = tile * 16 + g * 8 + slot;
                float s = 0.f;
                if (e < N_EDGES) {
                    const f32x4* row = base + (size_t)e * 32;
                    f32x4 a0 = __builtin_nontemporal_load(row + sub + 0);
                    f32x4 a1 = __builtin_nontemporal_load(row + sub + 8);
                    f32x4 a2 = __builtin_nontemporal_load(row + sub + 16);
                    f32x4 a3 = __builtin_nontemporal_load(row + sub + 24);
                    s = dot4(a0, b0) + dot4(a1, b1) + dot4(a2, b2) + dot4(a3, b3);
                }
                s += __shfl_xor(s, 1, 64);
                s += __shfl_xor(s, 2, 64);
                s += __shfl_xor(s, 4, 64);
                if (e < N_EDGES && sub < 3) {
                    const int   t = idx_t[e];
                    const float v = V_st[(size_t)e * 3 + sub];
                    atomicAdd(&frep[(size_t)t * 3 + sub], (s + bias) * v);
                }
            }
        }
    } else if (blockIdx.x < FPBLOCKS + EPBLOCKS) {
        // ---------------- energy ----------------
        const int wslot = (blockIdx.x - FPBLOCKS) * 4 + (threadIdx.x >> 6);
        const int slot  = lane >> 4;     // 0..3 : atom slot
        const int sub   = lane & 15;     // 0..15: position within atom row

        const f32x4* we   = reinterpret_cast<const f32x4*>(W_energy);
        const f32x4* base = reinterpret_cast<const f32x4*>(h_energy); // row = 64 f32x4
        float* yrep = ws + (wslot & (REP-1)) * YREP_STR;

        f32x4 b0 = we[sub + 0];
        f32x4 b1 = we[sub + 16];
        f32x4 b2 = we[sub + 32];
        f32x4 b3 = we[sub + 48];

        for (int tile = wslot; tile < ETILES; tile += EPBLOCKS * 4) {
            #pragma unroll
            for (int g = 0; g < 2; ++g) {
                const int a = tile * 8 + g * 4 + slot;   // < 100000 exact
                const f32x4* row = base + (size_t)a * 64;
                f32x4 a0 = __builtin_nontemporal_load(row + sub + 0);
                f32x4 a1 = __builtin_nontemporal_load(row + sub + 16);
                f32x4 a2 = __builtin_nontemporal_load(row + sub + 32);
                f32x4 a3 = __builtin_nontemporal_load(row + sub + 48);
                float s = dot4(a0, b0) + dot4(a1, b1) + dot4(a2, b2) + dot4(a3, b3);

                s += __shfl_xor(s, 1, 64);
                s += __shfl_xor(s, 2, 64);
                s += __shfl_xor(s, 4, 64);
                s += __shfl_xor(s, 8, 64);

                if (sub == 0) atomicAdd(&yrep[batch_idx[a]], s);
            }
        }
    }
}

extern "C" void kernel_launch(void* const* d_in, const int* in_sizes, int n_in,
                              void* d_out, int out_size, void* d_ws, size_t ws_size,
                              hipStream_t stream) {
    const float* h_energy  = (const float*)d_in[0];
    const float* h_forces  = (const float*)d_in[1];
    const float* V_st      = (const float*)d_in[2];
    const int*   idx_t     = (const int*)d_in[3];
    const int*   batch_idx = (const int*)d_in[4];
    const float* W_energy  = (const float*)d_in[5];
    const float* W_forces  = (const float*)d_in[6];
    const float* b_forces  = (const float*)d_in[7];

    float* ws  = (float*)d_ws;
    float* out = (float*)d_out;

    // Zero replica accumulators (2408192 floats = 602048 f32x4 = 9.6 MB).
    const int zn4 = WS_FLOATS / 4;
    zero_kernel<<<(zn4 + 255) / 256, 256, 0, stream>>>((f32x4*)d_ws, zn4);

    // Fused persistent kernel: 1172 forces + 364 energy blocks = 1536
    // (6 blocks/CU, all resident).
    fused_kernel<<<FPBLOCKS + EPBLOCKS, 256, 0, stream>>>(
        h_energy, h_forces, V_st, idx_t, batch_idx,
        W_energy, W_forces, b_forces, ws);

    // Merge replicas -> d_out (75250 f32x4 elements).
    merge_kernel<<<(75250 + 255) / 256, 256, 0, stream>>>(ws, out);
}